// Round 7
// baseline (220.191 us; speedup 1.0000x reference)
//
#include <hip/hip_runtime.h>

// Mamba-2 SSD chunked scan, 3-phase MFMA decomposition (round 7).
// Phase A: chunk_state = Xs^T B (MFMA), Xs = X*exp(cs63-cs).
// Phase B: prefix scan over chunks (in-place, unroll-4 batched prefetch).
// Phase C: G=C B^T -> M masked; Y = M@X + diag(e^{cs})*(C@Sp^T), Sp direct
//          from global. X^T staged into the C buffer AFTER phase 1 (C fully
//          consumed) -> LDS 28.2->18.9 KB, 8 blocks/CU (= kA's occupancy,
//          which runs at 5.4 TB/s vs kC's 3.1).

typedef __bf16 bf16x4 __attribute__((ext_vector_type(4)));
typedef __bf16 bf16x8 __attribute__((ext_vector_type(8)));
typedef float  f32x4  __attribute__((ext_vector_type(4)));

constexpr int LDT = 72;   // padded LDS row stride (bf16), 144 B (16B-aligned rows)

__device__ __forceinline__ f32x4 mfma16(bf16x8 a, bf16x8 b, f32x4 c) {
    return __builtin_amdgcn_mfma_f32_16x16x32_bf16(a, b, c, 0, 0, 0);
}

// ---------------- Phase A: chunk states ----------------
__global__ __launch_bounds__(256, 8)
void kA_chunkstate(const float* __restrict__ Xg, const float* __restrict__ Ag,
                   const float* __restrict__ Bg, __bf16* __restrict__ states,
                   float* __restrict__ cs63)
{
    const int cc = blockIdx.x, hh = blockIdx.y, bb = blockIdx.z;
    const int tid = threadIdx.x;
    __shared__ __bf16 sXt[64][LDT];   // Xs^T [p][l]  (later: out staging [p][n])
    __shared__ __bf16 sBt[64][LDT];   // B^T [n][l]
    __shared__ float  sds[64];
    const size_t tbase = (size_t)bb*4096 + (size_t)cc*64;
    const size_t slab  = (((size_t)bb*16 + hh)*64 + cc)*(size_t)4096;

    // ---- issue all global loads first ----
    const int lt0 = (tid >> 4) * 4;   // l block
    const int cq0 = (tid & 15) * 4;   // p/n col block
    float xr[4][4], br[4][4];
    #pragma unroll
    for (int j = 0; j < 4; ++j) {
        const size_t go = ((tbase + lt0 + j)*16 + hh)*(size_t)64 + cq0;
        *reinterpret_cast<float4*>(xr[j]) = *reinterpret_cast<const float4*>(&Xg[go]);
        *reinterpret_cast<float4*>(br[j]) = *reinterpret_cast<const float4*>(&Bg[go]);
    }
    // ---- A scan (wave 0) ----
    if (tid < 64) {
        float v = Ag[(tbase + tid)*16 + hh];
        #pragma unroll
        for (int o = 1; o < 64; o <<= 1) { float u = __shfl_up(v, o, 64); if (tid >= o) v += u; }
        const float last = __shfl(v, 63, 64);
        sds[tid] = expf(last - v);
        if (tid == 63) cs63[((size_t)bb*16 + hh)*64 + cc] = v;
    }
    // ---- B^T stage (4x4 reg transpose, no scan dependency) ----
    #pragma unroll
    for (int q = 0; q < 4; ++q)
        *reinterpret_cast<bf16x4*>(&sBt[cq0+q][lt0]) =
            (bf16x4){(__bf16)br[0][q], (__bf16)br[1][q],
                     (__bf16)br[2][q], (__bf16)br[3][q]};
    __syncthreads();   // S0: sds ready
    const float d0 = sds[lt0], d1 = sds[lt0+1], d2 = sds[lt0+2], d3 = sds[lt0+3];
    #pragma unroll
    for (int q = 0; q < 4; ++q)
        *reinterpret_cast<bf16x4*>(&sXt[cq0+q][lt0]) =
            (bf16x4){(__bf16)(xr[0][q]*d0), (__bf16)(xr[1][q]*d1),
                     (__bf16)(xr[2][q]*d2), (__bf16)(xr[3][q]*d3)};
    __syncthreads();   // S1: stage visible

    const int lane = tid & 63;
    const int wm = ((tid >> 7) & 1) * 32;
    const int wn = ((tid >> 6) & 1) * 32;
    const int fr = lane & 15, fg = lane >> 4;

    f32x4 acc[2][2] = {};
    #pragma unroll
    for (int ks = 0; ks < 2; ++ks) {
        const int k0 = ks*32 + fg*8;
        const bf16x8 a0 = *reinterpret_cast<const bf16x8*>(&sXt[wm      + fr][k0]);
        const bf16x8 a1 = *reinterpret_cast<const bf16x8*>(&sXt[wm + 16 + fr][k0]);
        const bf16x8 b0 = *reinterpret_cast<const bf16x8*>(&sBt[wn      + fr][k0]);
        const bf16x8 b1 = *reinterpret_cast<const bf16x8*>(&sBt[wn + 16 + fr][k0]);
        acc[0][0] = mfma16(a0, b0, acc[0][0]);
        acc[0][1] = mfma16(a0, b1, acc[0][1]);
        acc[1][0] = mfma16(a1, b0, acc[1][0]);
        acc[1][1] = mfma16(a1, b1, acc[1][1]);
    }
    __syncthreads();  // S2: all sXt/sBt reads done; overlay sXt with output

    __bf16 (*sOut)[LDT] = sXt;
    #pragma unroll
    for (int mt = 0; mt < 2; ++mt)
        #pragma unroll
        for (int nt = 0; nt < 2; ++nt)
            #pragma unroll
            for (int r = 0; r < 4; ++r)
                sOut[wm + 16*mt + fg*4 + r][wn + 16*nt + fr] = (__bf16)acc[mt][nt][r];
    __syncthreads();  // S3: sOut visible

    __bf16* dst = states + slab;
    #pragma unroll
    for (int it = 0; it < 2; ++it) {
        const int flat = tid + 256*it;
        const int p = flat >> 3, n8 = (flat & 7)*8;
        *reinterpret_cast<bf16x8*>(&dst[p*64 + n8]) =
            *reinterpret_cast<const bf16x8*>(&sOut[p][n8]);
    }
}

// ---------------- Phase B: prefix scan over chunks (in-place) ----------------
__global__ __launch_bounds__(256)
void kB_scan(const float* __restrict__ Ig, __bf16* __restrict__ states,
             const float* __restrict__ cs63)
{
    const int ph = blockIdx.x, hh = blockIdx.y, bb = blockIdx.z;
    const int tid = threadIdx.x;
    const int p  = ph*32 + (tid >> 3);
    const int n8 = (tid & 7) * 8;
    const float* ip = &Ig[(((size_t)bb*16 + hh)*64 + p)*(size_t)64 + n8];
    const float4 i0 = *reinterpret_cast<const float4*>(ip);
    const float4 i1 = *reinterpret_cast<const float4*>(ip + 4);
    float r[8] = {i0.x, i0.y, i0.z, i0.w, i1.x, i1.y, i1.z, i1.w};
    const float* csp = &cs63[((size_t)bb*16 + hh)*64];
    __bf16* sp = states + ((size_t)bb*16 + hh)*64*4096 + p*64 + n8;

    // Batched: 4 independent loads in flight per batch (only r is serial).
    for (int c0 = 0; c0 < 64; c0 += 4) {
        bf16x8 sv[4];
        float  dv[4];
        #pragma unroll
        for (int j = 0; j < 4; ++j) {
            sv[j] = *reinterpret_cast<const bf16x8*>(sp + (size_t)(c0 + j)*4096);
            dv[j] = expf(csp[c0 + j]);
        }
        #pragma unroll
        for (int j = 0; j < 4; ++j) {
            bf16x8 pr;
            #pragma unroll
            for (int e = 0; e < 8; ++e) pr[e] = (__bf16)r[e];
            *reinterpret_cast<bf16x8*>(sp + (size_t)(c0 + j)*4096) = pr;  // prefix
            #pragma unroll
            for (int e = 0; e < 8; ++e) r[e] = fmaf(dv[j], r[e], (float)sv[j][e]);
        }
    }
}

// ---------------- Phase C: outputs ----------------
struct SMemC {
    __bf16 CX[64][LDT];   // phase1: C [l][n]; phase2: X^T [p][l]  } sY overlay
    __bf16 BM[64][LDT];   // phase1: B [l][n]; phase2: M [i][j]    } after S4
    float  dout[64];      // e^{cs_i}   (lives past sY: offset > 17408)
    float  din[64];       // e^{-cs_j}
};

__global__ __launch_bounds__(256, 8)
void kC_output(const float* __restrict__ Xg, const float* __restrict__ Ag,
               const float* __restrict__ Bg, const float* __restrict__ Cg,
               const __bf16* __restrict__ states, float* __restrict__ Yg)
{
    const int cc = blockIdx.x, hh = blockIdx.y, bb = blockIdx.z;
    const int tid = threadIdx.x;
    __shared__ __align__(16) SMemC sm;
    const size_t tbase = (size_t)bb*4096 + (size_t)cc*64;
    const size_t slab  = (((size_t)bb*16 + hh)*64 + cc)*(size_t)4096;

    const int r0 = tid >> 4, c4 = (tid & 15) * 4;
    const int lt0 = (tid >> 4)*4, cq0 = (tid & 15) * 4;
    const int lane = tid & 63;
    const int wm = ((tid >> 7) & 1) * 32;
    const int wn = ((tid >> 6) & 1) * 32;
    const int fr = lane & 15, fg = lane >> 4;

    // ---- issue C, B, state loads upfront ----
    float cv[4][4], bv[4][4];
    #pragma unroll
    for (int it = 0; it < 4; ++it) {
        const size_t go = ((tbase + r0 + 16*it)*16 + hh)*(size_t)64 + c4;
        *reinterpret_cast<float4*>(cv[it]) = *reinterpret_cast<const float4*>(&Cg[go]);
        *reinterpret_cast<float4*>(bv[it]) = *reinterpret_cast<const float4*>(&Bg[go]);
    }
    const __bf16* stp = states + slab;
    bf16x8 spf[2][2];
    #pragma unroll
    for (int ks = 0; ks < 2; ++ks) {
        const int k0 = ks*32 + fg*8;
        spf[ks][0] = *reinterpret_cast<const bf16x8*>(&stp[(wn      + fr)*64 + k0]);
        spf[ks][1] = *reinterpret_cast<const bf16x8*>(&stp[(wn + 16 + fr)*64 + k0]);
    }

    // ---- A scan (wave 0) -> decay tables ----
    if (tid < 64) {
        float v = Ag[(tbase + tid)*16 + hh];
        #pragma unroll
        for (int o = 1; o < 64; o <<= 1) { float u = __shfl_up(v, o, 64); if (tid >= o) v += u; }
        sm.dout[tid] = expf(v);
        sm.din[tid]  = expf(-v);
    }

    // ---- stage C, B ----
    #pragma unroll
    for (int it = 0; it < 4; ++it) {
        const int l = r0 + 16*it;
        *reinterpret_cast<bf16x4*>(&sm.CX[l][c4]) =
            (bf16x4){(__bf16)cv[it][0], (__bf16)cv[it][1],
                     (__bf16)cv[it][2], (__bf16)cv[it][3]};
        *reinterpret_cast<bf16x4*>(&sm.BM[l][c4]) =
            (bf16x4){(__bf16)bv[it][0], (__bf16)bv[it][1],
                     (__bf16)bv[it][2], (__bf16)bv[it][3]};
    }
    __syncthreads();   // S1: stage + tables visible

    // ---- phase 1: G = C B^T  and  ao = C @ Sp^T (Sp frags from global) ----
    f32x4 g[2][2] = {}, ao[2][2] = {};
    #pragma unroll
    for (int ks = 0; ks < 2; ++ks) {
        const int k0 = ks*32 + fg*8;
        const bf16x8 a0 = *reinterpret_cast<const bf16x8*>(&sm.CX[wm      + fr][k0]);
        const bf16x8 a1 = *reinterpret_cast<const bf16x8*>(&sm.CX[wm + 16 + fr][k0]);
        const bf16x8 b0 = *reinterpret_cast<const bf16x8*>(&sm.BM[wn      + fr][k0]);
        const bf16x8 b1 = *reinterpret_cast<const bf16x8*>(&sm.BM[wn + 16 + fr][k0]);
        g[0][0] = mfma16(a0, b0, g[0][0]);
        g[0][1] = mfma16(a0, b1, g[0][1]);
        g[1][0] = mfma16(a1, b0, g[1][0]);
        g[1][1] = mfma16(a1, b1, g[1][1]);
        ao[0][0] = mfma16(a0, spf[ks][0], ao[0][0]);
        ao[0][1] = mfma16(a0, spf[ks][1], ao[0][1]);
        ao[1][0] = mfma16(a1, spf[ks][0], ao[1][0]);
        ao[1][1] = mfma16(a1, spf[ks][1], ao[1][1]);
    }
    __syncthreads();   // S2: all CX(C)/BM(B) reads done

    // ---- issue X loads now (latency covered by 8-block TLP + M write) ----
    float xr[4][4];
    #pragma unroll
    for (int j = 0; j < 4; ++j) {
        const size_t go = ((tbase + lt0 + j)*16 + hh)*(size_t)64 + cq0;
        *reinterpret_cast<float4*>(xr[j]) = *reinterpret_cast<const float4*>(&Xg[go]);
    }

    // ---- M = G * e^{cs_i} * e^{-cs_j}, masked -> overlay onto BM ----
    #pragma unroll
    for (int mt = 0; mt < 2; ++mt)
        #pragma unroll
        for (int nt = 0; nt < 2; ++nt) {
            const int j = wn + 16*nt + fr;
            const float dj = sm.din[j];
            #pragma unroll
            for (int r = 0; r < 4; ++r) {
                const int i = wm + 16*mt + fg*4 + r;
                const float val = (i >= j) ? g[mt][nt][r] * sm.dout[i] * dj : 0.0f;
                sm.BM[i][j] = (__bf16)val;
            }
        }
    // ---- stage X^T into CX (C fully consumed in phase 1) ----
    #pragma unroll
    for (int q = 0; q < 4; ++q)
        *reinterpret_cast<bf16x4*>(&sm.CX[cq0+q][lt0]) =
            (bf16x4){(__bf16)xr[0][q], (__bf16)xr[1][q],
                     (__bf16)xr[2][q], (__bf16)xr[3][q]};
    __syncthreads();   // S3: M + X^T fully written

    // ---- phase 2: ad = M @ X ----
    f32x4 ad[2][2] = {};
    #pragma unroll
    for (int ks = 0; ks < 2; ++ks) {
        const int k0 = ks*32 + fg*8;
        const bf16x8 m0 = *reinterpret_cast<const bf16x8*>(&sm.BM[wm      + fr][k0]);
        const bf16x8 m1 = *reinterpret_cast<const bf16x8*>(&sm.BM[wm + 16 + fr][k0]);
        const bf16x8 x0 = *reinterpret_cast<const bf16x8*>(&sm.CX[wn      + fr][k0]);
        const bf16x8 x1 = *reinterpret_cast<const bf16x8*>(&sm.CX[wn + 16 + fr][k0]);
        ad[0][0] = mfma16(m0, x0, ad[0][0]);
        ad[0][1] = mfma16(m0, x1, ad[0][1]);
        ad[1][0] = mfma16(m1, x0, ad[1][0]);
        ad[1][1] = mfma16(m1, x1, ad[1][1]);
    }
    __syncthreads();   // S4: all CX/BM reads done -> safe to overlay sY

    float (*sY)[68] = reinterpret_cast<float(*)[68]>(&sm);   // 17408 B over CX+BM
    #pragma unroll
    for (int mt = 0; mt < 2; ++mt)
        #pragma unroll
        for (int nt = 0; nt < 2; ++nt) {
            const int pcol = wn + 16*nt + fr;
            #pragma unroll
            for (int r = 0; r < 4; ++r) {
                const int i = wm + 16*mt + fg*4 + r;
                sY[i][pcol] = ad[mt][nt][r] + sm.dout[i]*ao[mt][nt][r];
            }
        }
    __syncthreads();   // S5

    #pragma unroll
    for (int it = 0; it < 4; ++it) {
        const int flat = tid + 256*it;
        const int row = flat >> 4;
        const int q4  = (flat & 15)*4;
        const float4 v = *reinterpret_cast<const float4*>(&sY[row][q4]);
        *reinterpret_cast<float4*>(&Yg[((tbase + row)*16 + hh)*(size_t)64 + q4]) = v;
    }
}

extern "C" void kernel_launch(void* const* d_in, const int* in_sizes, int n_in,
                              void* d_out, int out_size, void* d_ws, size_t ws_size,
                              hipStream_t stream) {
    const float* X  = (const float*)d_in[0];
    const float* I  = (const float*)d_in[1];
    const float* A  = (const float*)d_in[2];
    const float* Bp = (const float*)d_in[3];
    const float* Cp = (const float*)d_in[4];
    float* Y = (float*)d_out;
    __bf16* states = (__bf16*)d_ws;                                   // 67,108,864 B
    float*  cs63   = (float*)((char*)d_ws + (size_t)67108864);        //     32,768 B

    kA_chunkstate<<<dim3(64,16,8), 256, 0, stream>>>(X, A, Bp, states, cs63);
    kB_scan      <<<dim3(2,16,8),  256, 0, stream>>>(I, states, cs63);
    kC_output    <<<dim3(64,16,8), 256, 0, stream>>>(X, A, Bp, Cp, states, Y);
}

// Round 8
// 216.180 us; speedup vs baseline: 1.0186x; 1.0186x over previous
//
#include <hip/hip_runtime.h>

// Mamba-2 SSD chunked scan, 3-phase MFMA decomposition (round 8).
// Phase A: chunk_state = Xs^T B (MFMA), Xs = X*exp(cs63-cs).
// Phase B: prefix scan over chunks (in-place, unroll-4 batched prefetch).
// Phase C: G=C B^T -> M masked; Y = M@X + diag(e^{cs})*(C@Sp^T), Sp direct
//          from global; X^T staged into the consumed C buffer (18.9 KB LDS).
// Round-8: r7's launch_bounds(256,8) caused scratch spill (VGPR=32,
// WRITE_SIZE +89MB). Relax to (256,6) (~85 VGPR cap: 32 load regs fit) and
// pin upfront load issue with sched_barrier(0) (r5 kA VGPR=24 = load-sinking
// signature). Canary: WRITE_SIZE must be 131072 KB exactly.

typedef __bf16 bf16x4 __attribute__((ext_vector_type(4)));
typedef __bf16 bf16x8 __attribute__((ext_vector_type(8)));
typedef float  f32x4  __attribute__((ext_vector_type(4)));

constexpr int LDT = 72;   // padded LDS row stride (bf16), 144 B (16B-aligned rows)

__device__ __forceinline__ f32x4 mfma16(bf16x8 a, bf16x8 b, f32x4 c) {
    return __builtin_amdgcn_mfma_f32_16x16x32_bf16(a, b, c, 0, 0, 0);
}

// ---------------- Phase A: chunk states ----------------
__global__ __launch_bounds__(256, 6)
void kA_chunkstate(const float* __restrict__ Xg, const float* __restrict__ Ag,
                   const float* __restrict__ Bg, __bf16* __restrict__ states,
                   float* __restrict__ cs63)
{
    const int cc = blockIdx.x, hh = blockIdx.y, bb = blockIdx.z;
    const int tid = threadIdx.x;
    __shared__ __bf16 sXt[64][LDT];   // Xs^T [p][l]  (later: out staging [p][n])
    __shared__ __bf16 sBt[64][LDT];   // B^T [n][l]
    __shared__ float  sds[64];
    const size_t tbase = (size_t)bb*4096 + (size_t)cc*64;
    const size_t slab  = (((size_t)bb*16 + hh)*64 + cc)*(size_t)4096;

    // ---- issue all global loads first (pinned: do not sink past scan) ----
    const int lt0 = (tid >> 4) * 4;   // l block
    const int cq0 = (tid & 15) * 4;   // p/n col block
    float xr[4][4], br[4][4];
    #pragma unroll
    for (int j = 0; j < 4; ++j) {
        const size_t go = ((tbase + lt0 + j)*16 + hh)*(size_t)64 + cq0;
        *reinterpret_cast<float4*>(br[j]) = *reinterpret_cast<const float4*>(&Bg[go]);
        *reinterpret_cast<float4*>(xr[j]) = *reinterpret_cast<const float4*>(&Xg[go]);
    }
    __builtin_amdgcn_sched_barrier(0);   // keep loads issued here

    // ---- A scan (wave 0) ----
    if (tid < 64) {
        float v = Ag[(tbase + tid)*16 + hh];
        #pragma unroll
        for (int o = 1; o < 64; o <<= 1) { float u = __shfl_up(v, o, 64); if (tid >= o) v += u; }
        const float last = __shfl(v, 63, 64);
        sds[tid] = expf(last - v);
        if (tid == 63) cs63[((size_t)bb*16 + hh)*64 + cc] = v;
    }
    // ---- B^T stage (4x4 reg transpose, no scan dependency) ----
    #pragma unroll
    for (int q = 0; q < 4; ++q)
        *reinterpret_cast<bf16x4*>(&sBt[cq0+q][lt0]) =
            (bf16x4){(__bf16)br[0][q], (__bf16)br[1][q],
                     (__bf16)br[2][q], (__bf16)br[3][q]};
    __syncthreads();   // S0: sds ready
    const float d0 = sds[lt0], d1 = sds[lt0+1], d2 = sds[lt0+2], d3 = sds[lt0+3];
    #pragma unroll
    for (int q = 0; q < 4; ++q)
        *reinterpret_cast<bf16x4*>(&sXt[cq0+q][lt0]) =
            (bf16x4){(__bf16)(xr[0][q]*d0), (__bf16)(xr[1][q]*d1),
                     (__bf16)(xr[2][q]*d2), (__bf16)(xr[3][q]*d3)};
    __syncthreads();   // S1: stage visible

    const int lane = tid & 63;
    const int wm = ((tid >> 7) & 1) * 32;
    const int wn = ((tid >> 6) & 1) * 32;
    const int fr = lane & 15, fg = lane >> 4;

    f32x4 acc[2][2] = {};
    #pragma unroll
    for (int ks = 0; ks < 2; ++ks) {
        const int k0 = ks*32 + fg*8;
        const bf16x8 a0 = *reinterpret_cast<const bf16x8*>(&sXt[wm      + fr][k0]);
        const bf16x8 a1 = *reinterpret_cast<const bf16x8*>(&sXt[wm + 16 + fr][k0]);
        const bf16x8 b0 = *reinterpret_cast<const bf16x8*>(&sBt[wn      + fr][k0]);
        const bf16x8 b1 = *reinterpret_cast<const bf16x8*>(&sBt[wn + 16 + fr][k0]);
        acc[0][0] = mfma16(a0, b0, acc[0][0]);
        acc[0][1] = mfma16(a0, b1, acc[0][1]);
        acc[1][0] = mfma16(a1, b0, acc[1][0]);
        acc[1][1] = mfma16(a1, b1, acc[1][1]);
    }
    __syncthreads();  // S2: all sXt/sBt reads done; overlay sXt with output

    __bf16 (*sOut)[LDT] = sXt;
    #pragma unroll
    for (int mt = 0; mt < 2; ++mt)
        #pragma unroll
        for (int nt = 0; nt < 2; ++nt)
            #pragma unroll
            for (int r = 0; r < 4; ++r)
                sOut[wm + 16*mt + fg*4 + r][wn + 16*nt + fr] = (__bf16)acc[mt][nt][r];
    __syncthreads();  // S3: sOut visible

    __bf16* dst = states + slab;
    #pragma unroll
    for (int it = 0; it < 2; ++it) {
        const int flat = tid + 256*it;
        const int p = flat >> 3, n8 = (flat & 7)*8;
        *reinterpret_cast<bf16x8*>(&dst[p*64 + n8]) =
            *reinterpret_cast<const bf16x8*>(&sOut[p][n8]);
    }
}

// ---------------- Phase B: prefix scan over chunks (in-place) ----------------
__global__ __launch_bounds__(256)
void kB_scan(const float* __restrict__ Ig, __bf16* __restrict__ states,
             const float* __restrict__ cs63)
{
    const int ph = blockIdx.x, hh = blockIdx.y, bb = blockIdx.z;
    const int tid = threadIdx.x;
    const int p  = ph*32 + (tid >> 3);
    const int n8 = (tid & 7) * 8;
    const float* ip = &Ig[(((size_t)bb*16 + hh)*64 + p)*(size_t)64 + n8];
    const float4 i0 = *reinterpret_cast<const float4*>(ip);
    const float4 i1 = *reinterpret_cast<const float4*>(ip + 4);
    float r[8] = {i0.x, i0.y, i0.z, i0.w, i1.x, i1.y, i1.z, i1.w};
    const float* csp = &cs63[((size_t)bb*16 + hh)*64];
    __bf16* sp = states + ((size_t)bb*16 + hh)*64*4096 + p*64 + n8;

    // Batched: 4 independent loads in flight per batch (only r is serial).
    for (int c0 = 0; c0 < 64; c0 += 4) {
        bf16x8 sv[4];
        float  dv[4];
        #pragma unroll
        for (int j = 0; j < 4; ++j) {
            sv[j] = *reinterpret_cast<const bf16x8*>(sp + (size_t)(c0 + j)*4096);
            dv[j] = expf(csp[c0 + j]);
        }
        #pragma unroll
        for (int j = 0; j < 4; ++j) {
            bf16x8 pr;
            #pragma unroll
            for (int e = 0; e < 8; ++e) pr[e] = (__bf16)r[e];
            *reinterpret_cast<bf16x8*>(sp + (size_t)(c0 + j)*4096) = pr;  // prefix
            #pragma unroll
            for (int e = 0; e < 8; ++e) r[e] = fmaf(dv[j], r[e], (float)sv[j][e]);
        }
    }
}

// ---------------- Phase C: outputs ----------------
struct SMemC {
    __bf16 CX[64][LDT];   // phase1: C [l][n]; phase2: X^T [p][l]  } sY overlay
    __bf16 BM[64][LDT];   // phase1: B [l][n]; phase2: M [i][j]    } after S4
    float  dout[64];      // e^{cs_i}   (offset 18432 > sY's 17408: survives)
    float  din[64];       // e^{-cs_j}
};

__global__ __launch_bounds__(256, 6)
void kC_output(const float* __restrict__ Xg, const float* __restrict__ Ag,
               const float* __restrict__ Bg, const float* __restrict__ Cg,
               const __bf16* __restrict__ states, float* __restrict__ Yg)
{
    const int cc = blockIdx.x, hh = blockIdx.y, bb = blockIdx.z;
    const int tid = threadIdx.x;
    __shared__ __align__(16) SMemC sm;
    const size_t tbase = (size_t)bb*4096 + (size_t)cc*64;
    const size_t slab  = (((size_t)bb*16 + hh)*64 + cc)*(size_t)4096;

    const int r0 = tid >> 4, c4 = (tid & 15) * 4;
    const int lt0 = (tid >> 4)*4, cq0 = (tid & 15) * 4;
    const int lane = tid & 63;
    const int wm = ((tid >> 7) & 1) * 32;
    const int wn = ((tid >> 6) & 1) * 32;
    const int fr = lane & 15, fg = lane >> 4;

    // ---- issue C, B, state loads upfront (pinned) ----
    float cv[4][4], bv[4][4];
    #pragma unroll
    for (int it = 0; it < 4; ++it) {
        const size_t go = ((tbase + r0 + 16*it)*16 + hh)*(size_t)64 + c4;
        *reinterpret_cast<float4*>(cv[it]) = *reinterpret_cast<const float4*>(&Cg[go]);
        *reinterpret_cast<float4*>(bv[it]) = *reinterpret_cast<const float4*>(&Bg[go]);
    }
    const __bf16* stp = states + slab;
    bf16x8 spf[2][2];
    #pragma unroll
    for (int ks = 0; ks < 2; ++ks) {
        const int k0 = ks*32 + fg*8;
        spf[ks][0] = *reinterpret_cast<const bf16x8*>(&stp[(wn      + fr)*64 + k0]);
        spf[ks][1] = *reinterpret_cast<const bf16x8*>(&stp[(wn + 16 + fr)*64 + k0]);
    }
    __builtin_amdgcn_sched_barrier(0);   // keep loads issued here

    // ---- A scan (wave 0) -> decay tables ----
    if (tid < 64) {
        float v = Ag[(tbase + tid)*16 + hh];
        #pragma unroll
        for (int o = 1; o < 64; o <<= 1) { float u = __shfl_up(v, o, 64); if (tid >= o) v += u; }
        sm.dout[tid] = expf(v);
        sm.din[tid]  = expf(-v);
    }

    // ---- stage C, B ----
    #pragma unroll
    for (int it = 0; it < 4; ++it) {
        const int l = r0 + 16*it;
        *reinterpret_cast<bf16x4*>(&sm.CX[l][c4]) =
            (bf16x4){(__bf16)cv[it][0], (__bf16)cv[it][1],
                     (__bf16)cv[it][2], (__bf16)cv[it][3]};
        *reinterpret_cast<bf16x4*>(&sm.BM[l][c4]) =
            (bf16x4){(__bf16)bv[it][0], (__bf16)bv[it][1],
                     (__bf16)bv[it][2], (__bf16)bv[it][3]};
    }
    __syncthreads();   // S1: stage + tables visible

    // ---- phase 1: G = C B^T  and  ao = C @ Sp^T (Sp frags from global) ----
    f32x4 g[2][2] = {}, ao[2][2] = {};
    #pragma unroll
    for (int ks = 0; ks < 2; ++ks) {
        const int k0 = ks*32 + fg*8;
        const bf16x8 a0 = *reinterpret_cast<const bf16x8*>(&sm.CX[wm      + fr][k0]);
        const bf16x8 a1 = *reinterpret_cast<const bf16x8*>(&sm.CX[wm + 16 + fr][k0]);
        const bf16x8 b0 = *reinterpret_cast<const bf16x8*>(&sm.BM[wn      + fr][k0]);
        const bf16x8 b1 = *reinterpret_cast<const bf16x8*>(&sm.BM[wn + 16 + fr][k0]);
        g[0][0] = mfma16(a0, b0, g[0][0]);
        g[0][1] = mfma16(a0, b1, g[0][1]);
        g[1][0] = mfma16(a1, b0, g[1][0]);
        g[1][1] = mfma16(a1, b1, g[1][1]);
        ao[0][0] = mfma16(a0, spf[ks][0], ao[0][0]);
        ao[0][1] = mfma16(a0, spf[ks][1], ao[0][1]);
        ao[1][0] = mfma16(a1, spf[ks][0], ao[1][0]);
        ao[1][1] = mfma16(a1, spf[ks][1], ao[1][1]);
    }
    __syncthreads();   // S2: all CX(C)/BM(B) reads done

    // ---- issue X loads now (latency covered by M write + other blocks) ----
    float xr[4][4];
    #pragma unroll
    for (int j = 0; j < 4; ++j) {
        const size_t go = ((tbase + lt0 + j)*16 + hh)*(size_t)64 + cq0;
        *reinterpret_cast<float4*>(xr[j]) = *reinterpret_cast<const float4*>(&Xg[go]);
    }
    __builtin_amdgcn_sched_barrier(0);   // keep X loads issued here

    // ---- M = G * e^{cs_i} * e^{-cs_j}, masked -> overlay onto BM ----
    #pragma unroll
    for (int mt = 0; mt < 2; ++mt)
        #pragma unroll
        for (int nt = 0; nt < 2; ++nt) {
            const int j = wn + 16*nt + fr;
            const float dj = sm.din[j];
            #pragma unroll
            for (int r = 0; r < 4; ++r) {
                const int i = wm + 16*mt + fg*4 + r;
                const float val = (i >= j) ? g[mt][nt][r] * sm.dout[i] * dj : 0.0f;
                sm.BM[i][j] = (__bf16)val;
            }
        }
    // ---- stage X^T into CX (C fully consumed in phase 1) ----
    #pragma unroll
    for (int q = 0; q < 4; ++q)
        *reinterpret_cast<bf16x4*>(&sm.CX[cq0+q][lt0]) =
            (bf16x4){(__bf16)xr[0][q], (__bf16)xr[1][q],
                     (__bf16)xr[2][q], (__bf16)xr[3][q]};
    __syncthreads();   // S3: M + X^T fully written

    // ---- phase 2: ad = M @ X ----
    f32x4 ad[2][2] = {};
    #pragma unroll
    for (int ks = 0; ks < 2; ++ks) {
        const int k0 = ks*32 + fg*8;
        const bf16x8 m0 = *reinterpret_cast<const bf16x8*>(&sm.BM[wm      + fr][k0]);
        const bf16x8 m1 = *reinterpret_cast<const bf16x8*>(&sm.BM[wm + 16 + fr][k0]);
        const bf16x8 x0 = *reinterpret_cast<const bf16x8*>(&sm.CX[wn      + fr][k0]);
        const bf16x8 x1 = *reinterpret_cast<const bf16x8*>(&sm.CX[wn + 16 + fr][k0]);
        ad[0][0] = mfma16(m0, x0, ad[0][0]);
        ad[0][1] = mfma16(m0, x1, ad[0][1]);
        ad[1][0] = mfma16(m1, x0, ad[1][0]);
        ad[1][1] = mfma16(m1, x1, ad[1][1]);
    }
    __syncthreads();   // S4: all CX/BM reads done -> safe to overlay sY

    float (*sY)[68] = reinterpret_cast<float(*)[68]>(&sm);   // 17408 B over CX+BM
    #pragma unroll
    for (int mt = 0; mt < 2; ++mt)
        #pragma unroll
        for (int nt = 0; nt < 2; ++nt) {
            const int pcol = wn + 16*nt + fr;
            #pragma unroll
            for (int r = 0; r < 4; ++r) {
                const int i = wm + 16*mt + fg*4 + r;
                sY[i][pcol] = ad[mt][nt][r] + sm.dout[i]*ao[mt][nt][r];
            }
        }
    __syncthreads();   // S5

    #pragma unroll
    for (int it = 0; it < 4; ++it) {
        const int flat = tid + 256*it;
        const int row = flat >> 4;
        const int q4  = (flat & 15)*4;
        const float4 v = *reinterpret_cast<const float4*>(&sY[row][q4]);
        *reinterpret_cast<float4*>(&Yg[((tbase + row)*16 + hh)*(size_t)64 + q4]) = v;
    }
}

extern "C" void kernel_launch(void* const* d_in, const int* in_sizes, int n_in,
                              void* d_out, int out_size, void* d_ws, size_t ws_size,
                              hipStream_t stream) {
    const float* X  = (const float*)d_in[0];
    const float* I  = (const float*)d_in[1];
    const float* A  = (const float*)d_in[2];
    const float* Bp = (const float*)d_in[3];
    const float* Cp = (const float*)d_in[4];
    float* Y = (float*)d_out;
    __bf16* states = (__bf16*)d_ws;                                   // 67,108,864 B
    float*  cs63   = (float*)((char*)d_ws + (size_t)67108864);        //     32,768 B

    kA_chunkstate<<<dim3(64,16,8), 256, 0, stream>>>(X, A, Bp, states, cs63);
    kB_scan      <<<dim3(2,16,8),  256, 0, stream>>>(I, states, cs63);
    kC_output    <<<dim3(64,16,8), 256, 0, stream>>>(X, A, Bp, Cp, states, Y);
}

// Round 9
// 178.482 us; speedup vs baseline: 1.2337x; 1.2112x over previous
//
#include <hip/hip_runtime.h>

// Mamba-2 SSD chunked scan — SINGLE fused persistent kernel (round 9).
// Block = (p-half, h, b): 256 blocks x 512 threads (8 waves). The chunk-prefix
// state St (32p x 64n) lives in LDS (f32 master + bf16 operand copy) across a
// sequential 64-chunk loop. Per chunk c:
//   P1: G = C B^T ; ao = C St^T ; stch^T = (B^T-frags) x (Xs^T-frags)   [MFMA]
//   P2: M' = mask(G) * e^{cs_i-cs63} -> LDS ; St = e^{cs63} St + stch ;
//       stage chunk c+1 (C,B,B^T,Xs^T) ; issue global loads for c+2
//   P3: ad = M' Xs ; Y = ad + e^{cs} o ao -> sY
//   P4: coalesced float4 Y store
// Removes kA/kB/kC pipeline + 268MB ws round-trip. Y_diag uses the r5-proven
// identity M'·Xs = G e^{cs_i-cs_j} X. 3 barriers/iter. No launch_bounds
// (rounds 5/7/8: VGPR caps + reg prefetch => scratch spill; canary:
// WRITE_SIZE must be exactly 131072 KB).

typedef __bf16 bf16x4 __attribute__((ext_vector_type(4)));
typedef __bf16 bf16x8 __attribute__((ext_vector_type(8)));
typedef float  f32x4  __attribute__((ext_vector_type(4)));

constexpr int LDT = 72;   // bf16 row stride (144 B)

__device__ __forceinline__ f32x4 mfma16(bf16x8 a, bf16x8 b, f32x4 c) {
    return __builtin_amdgcn_mfma_f32_16x16x32_bf16(a, b, c, 0, 0, 0);
}

struct SMemF {
    __bf16 Cm[64][LDT];      // C row-major [l][n]
    __bf16 Bm[64][LDT];      // B row-major [l][n]
    __bf16 Bt[64][LDT];      // B^T [n][l]
    __bf16 Mm[64][LDT];      // M' [i][j]
    __bf16 Xt[2][32][LDT];   // Xs^T [p][l], double-buffered
    __bf16 St16[32][LDT];    // state bf16 (operand copy)
    float  St32[32][68];     // state f32 (master)
    float  sY[64][36];       // Y staging (p-half)
    float  ds[2][64];        // e^{cs63-cs_l}
    float  dout[2][64];      // e^{cs_i}
    float  douti[2][64];     // e^{cs_i-cs63}
    float  dlast[2];         // e^{cs63}
};

__global__ void ssd_fused(const float* __restrict__ Xg, const float* __restrict__ Ig,
                          const float* __restrict__ Ag, const float* __restrict__ Bg,
                          const float* __restrict__ Cg, float* __restrict__ Yg)
{
    const int ph = blockIdx.x, hh = blockIdx.y, bb = blockIdx.z;
    const int tid = threadIdx.x;            // 0..511
    const int wid = tid >> 6, lane = tid & 63;
    const int fr = lane & 15, fg = lane >> 4;
    const int iw2 = (wid >> 1) * 16;        // i-strip (also st n-strip)
    const int pt  = (wid & 1) * 16;         // p-tile
    const int jh  = (wid & 1) * 32;         // G j-half base

    __shared__ __align__(16) SMemF sm;
    const size_t tbase = (size_t)bb * 4096;

    // staging role split
    const int half = tid >> 8;              // 0: B rows (flat+transpose), 1: C rows
    const int u    = tid & 255;
    const int lt0  = (u >> 4) * 4;          // B: 4-row block
    const int rr0  = u >> 4;                // C: base row
    const int cq0  = (u & 15) * 4;          // column quad
    // X / Y map
    const int xl  = tid >> 3;               // 0..63
    const int xp4 = (tid & 7) * 4;          // 0..28
    // St init map
    const int sp  = tid >> 4;               // 0..31
    const int sn4 = (tid & 15) * 4;

    float rb[4][4];   // B or C rows (per role)
    float rx[4];      // X row segment
    float aA = 0.0f;  // wave0: A value for next scan

    // ---------------- prologue ----------------
    // initial state
    {
        const size_t iofs = (((size_t)bb*16 + hh)*64 + (ph*32 + sp))*(size_t)64 + sn4;
        const float4 v = *reinterpret_cast<const float4*>(&Ig[iofs]);
        sm.St32[sp][sn4+0] = v.x; sm.St32[sp][sn4+1] = v.y;
        sm.St32[sp][sn4+2] = v.z; sm.St32[sp][sn4+3] = v.w;
        *reinterpret_cast<bf16x4*>(&sm.St16[sp][sn4]) =
            (bf16x4){(__bf16)v.x, (__bf16)v.y, (__bf16)v.z, (__bf16)v.w};
    }
    // chunk-0 loads
    #pragma unroll
    for (int j = 0; j < 4; ++j) {
        const int row = (half == 0) ? (lt0 + j) : (rr0 + 16*j);
        const size_t go = ((tbase + row)*16 + hh)*(size_t)64 + cq0;
        *reinterpret_cast<float4*>(rb[j]) = (half == 0)
            ? *reinterpret_cast<const float4*>(&Bg[go])
            : *reinterpret_cast<const float4*>(&Cg[go]);
    }
    *reinterpret_cast<float4*>(rx) =
        *reinterpret_cast<const float4*>(&Xg[((tbase + xl)*16 + hh)*(size_t)64 + ph*32 + xp4]);
    if (wid == 0) aA = Ag[(tbase + lane)*16 + hh];

    // scan chunk 0 -> tables[0]
    if (wid == 0) {
        float v = aA;
        #pragma unroll
        for (int o = 1; o < 64; o <<= 1) { float t = __shfl_up(v, o, 64); if (lane >= o) v += t; }
        const float last = __shfl(v, 63, 64);
        sm.ds[0][lane]    = expf(last - v);
        sm.dout[0][lane]  = expf(v);
        sm.douti[0][lane] = expf(v - last);
        if (lane == 63) sm.dlast[0] = expf(v);
    }
    // stage chunk-0 C/B/Bt (no table dependency)
    if (half == 0) {
        #pragma unroll
        for (int j = 0; j < 4; ++j)
            *reinterpret_cast<bf16x4*>(&sm.Bm[lt0 + j][cq0]) =
                (bf16x4){(__bf16)rb[j][0], (__bf16)rb[j][1], (__bf16)rb[j][2], (__bf16)rb[j][3]};
        #pragma unroll
        for (int q = 0; q < 4; ++q)
            *reinterpret_cast<bf16x4*>(&sm.Bt[cq0 + q][lt0]) =
                (bf16x4){(__bf16)rb[0][q], (__bf16)rb[1][q], (__bf16)rb[2][q], (__bf16)rb[3][q]};
    } else {
        #pragma unroll
        for (int j = 0; j < 4; ++j)
            *reinterpret_cast<bf16x4*>(&sm.Cm[rr0 + 16*j][cq0]) =
                (bf16x4){(__bf16)rb[j][0], (__bf16)rb[j][1], (__bf16)rb[j][2], (__bf16)rb[j][3]};
    }
    __syncthreads();   // tables[0] + St ready
    // stage Xs^T[0] (needs ds[0])
    {
        const float dsl = sm.ds[0][xl];
        #pragma unroll
        for (int q = 0; q < 4; ++q) sm.Xt[0][xp4 + q][xl] = (__bf16)(rx[q] * dsl);
    }
    // chunk-1 loads
    #pragma unroll
    for (int j = 0; j < 4; ++j) {
        const int row = (half == 0) ? (lt0 + j) : (rr0 + 16*j);
        const size_t go = ((tbase + 64 + row)*16 + hh)*(size_t)64 + cq0;
        *reinterpret_cast<float4*>(rb[j]) = (half == 0)
            ? *reinterpret_cast<const float4*>(&Bg[go])
            : *reinterpret_cast<const float4*>(&Cg[go]);
    }
    *reinterpret_cast<float4*>(rx) =
        *reinterpret_cast<const float4*>(&Xg[((tbase + 64 + xl)*16 + hh)*(size_t)64 + ph*32 + xp4]);
    if (wid == 0) aA = Ag[(tbase + 64 + lane)*16 + hh];
    __syncthreads();   // Xt[0] visible

    // ---------------- chunk loop ----------------
    for (int c = 0; c < 64; ++c) {
        const int ci = c & 1, nb = (c + 1) & 1;

        // ---- P1: MFMAs for chunk c (+ wave0 scans c+1) ----
        f32x4 g0 = {}, g1 = {}, aoacc = {}, stacc = {};
        #pragma unroll
        for (int ks = 0; ks < 2; ++ks) {
            const int k0 = ks*32 + fg*8;
            const bf16x8 aC  = *reinterpret_cast<const bf16x8*>(&sm.Cm[iw2 + fr][k0]);
            const bf16x8 bB0 = *reinterpret_cast<const bf16x8*>(&sm.Bm[jh      + fr][k0]);
            const bf16x8 bB1 = *reinterpret_cast<const bf16x8*>(&sm.Bm[jh + 16 + fr][k0]);
            const bf16x8 bSt = *reinterpret_cast<const bf16x8*>(&sm.St16[pt + fr][k0]);
            const bf16x8 aBt = *reinterpret_cast<const bf16x8*>(&sm.Bt[iw2 + fr][k0]);
            const bf16x8 bXt = *reinterpret_cast<const bf16x8*>(&sm.Xt[ci][pt + fr][k0]);
            g0    = mfma16(aC,  bB0, g0);
            g1    = mfma16(aC,  bB1, g1);
            aoacc = mfma16(aC,  bSt, aoacc);
            stacc = mfma16(aBt, bXt, stacc);
        }
        if (c < 63 && wid == 0) {
            float v = aA;
            #pragma unroll
            for (int o = 1; o < 64; o <<= 1) { float t = __shfl_up(v, o, 64); if (lane >= o) v += t; }
            const float last = __shfl(v, 63, 64);
            sm.ds[nb][lane]    = expf(last - v);
            sm.dout[nb][lane]  = expf(v);
            sm.douti[nb][lane] = expf(v - last);
            if (lane == 63) sm.dlast[nb] = expf(v);
        }
        __syncthreads();   // S2

        // ---- P2: M' write, St update, stage c+1, issue loads c+2 ----
        {
            const float dl = sm.dlast[ci];
            #pragma unroll
            for (int jt = 0; jt < 2; ++jt) {
                const int j = jh + jt*16 + fr;
                const f32x4& gg = jt ? g1 : g0;
                #pragma unroll
                for (int r = 0; r < 4; ++r) {
                    const int i = iw2 + fg*4 + r;
                    const float val = (i >= j) ? gg[r] * sm.douti[ci][i] : 0.0f;
                    sm.Mm[i][j] = (__bf16)val;
                }
            }
            #pragma unroll
            for (int r = 0; r < 4; ++r) {
                const int p = pt + fr, n = iw2 + fg*4 + r;
                const float nv = fmaf(dl, sm.St32[p][n], stacc[r]);
                sm.St32[p][n] = nv;
                sm.St16[p][n] = (__bf16)nv;
            }
        }
        if (c < 63) {
            if (half == 0) {
                #pragma unroll
                for (int j = 0; j < 4; ++j)
                    *reinterpret_cast<bf16x4*>(&sm.Bm[lt0 + j][cq0]) =
                        (bf16x4){(__bf16)rb[j][0], (__bf16)rb[j][1], (__bf16)rb[j][2], (__bf16)rb[j][3]};
                #pragma unroll
                for (int q = 0; q < 4; ++q)
                    *reinterpret_cast<bf16x4*>(&sm.Bt[cq0 + q][lt0]) =
                        (bf16x4){(__bf16)rb[0][q], (__bf16)rb[1][q], (__bf16)rb[2][q], (__bf16)rb[3][q]};
            } else {
                #pragma unroll
                for (int j = 0; j < 4; ++j)
                    *reinterpret_cast<bf16x4*>(&sm.Cm[rr0 + 16*j][cq0]) =
                        (bf16x4){(__bf16)rb[j][0], (__bf16)rb[j][1], (__bf16)rb[j][2], (__bf16)rb[j][3]};
            }
            const float dsl = sm.ds[nb][xl];
            #pragma unroll
            for (int q = 0; q < 4; ++q) sm.Xt[nb][xp4 + q][xl] = (__bf16)(rx[q] * dsl);
        }
        if (c < 62) {
            const size_t s2 = tbase + (size_t)(c + 2)*64;
            #pragma unroll
            for (int j = 0; j < 4; ++j) {
                const int row = (half == 0) ? (lt0 + j) : (rr0 + 16*j);
                const size_t go = ((s2 + row)*16 + hh)*(size_t)64 + cq0;
                *reinterpret_cast<float4*>(rb[j]) = (half == 0)
                    ? *reinterpret_cast<const float4*>(&Bg[go])
                    : *reinterpret_cast<const float4*>(&Cg[go]);
            }
            *reinterpret_cast<float4*>(rx) =
                *reinterpret_cast<const float4*>(&Xg[((s2 + xl)*16 + hh)*(size_t)64 + ph*32 + xp4]);
            if (wid == 0) aA = Ag[(s2 + lane)*16 + hh];
        }
        __syncthreads();   // S3

        // ---- P3: ad = M' Xs ; Y -> sY ----
        {
            f32x4 ad = {};
            #pragma unroll
            for (int ks = 0; ks < 2; ++ks) {
                const int k0 = ks*32 + fg*8;
                const bf16x8 aM = *reinterpret_cast<const bf16x8*>(&sm.Mm[iw2 + fr][k0]);
                const bf16x8 bX = *reinterpret_cast<const bf16x8*>(&sm.Xt[ci][pt + fr][k0]);
                ad = mfma16(aM, bX, ad);
            }
            #pragma unroll
            for (int r = 0; r < 4; ++r) {
                const int i = iw2 + fg*4 + r;
                sm.sY[i][pt + fr] = ad[r] + sm.dout[ci][i] * aoacc[r];
            }
        }
        __syncthreads();   // S4

        // ---- P4: coalesced Y store ----
        {
            const float4 v = *reinterpret_cast<const float4*>(&sm.sY[xl][xp4]);
            *reinterpret_cast<float4*>(
                &Yg[((tbase + (size_t)c*64 + xl)*16 + hh)*(size_t)64 + ph*32 + xp4]) = v;
        }
        // no barrier needed here: next writer of sY is P3(c+1), after S2+S3;
        // stage buffers' next writer is P2(c+1), after S2.
    }
}

extern "C" void kernel_launch(void* const* d_in, const int* in_sizes, int n_in,
                              void* d_out, int out_size, void* d_ws, size_t ws_size,
                              hipStream_t stream) {
    const float* X  = (const float*)d_in[0];
    const float* I  = (const float*)d_in[1];
    const float* A  = (const float*)d_in[2];
    const float* Bp = (const float*)d_in[3];
    const float* Cp = (const float*)d_in[4];
    float* Y = (float*)d_out;
    ssd_fused<<<dim3(2, 16, 8), 512, 0, stream>>>(X, I, A, Bp, Cp, Y);
}